// Round 12
// baseline (1825.776 us; speedup 1.0000x reference)
//
#include <hip/hip_runtime.h>
#include <stdint.h>

using half8 = __attribute__((ext_vector_type(8))) _Float16;
using half4 = __attribute__((ext_vector_type(4))) _Float16;
using f32x4 = __attribute__((ext_vector_type(4))) float;

#define BM 256
#define BN 128
#define BK 32

// Bank-conflict-free B layout: granule (row, k8) at byte row*64 + (k8^((row>>1)&3))*16.
// Read side uses swz(); GLD staging realizes it via pre-swizzled global source
// addresses (LDS dest must be linear: wave-uniform base + lane*16).
__device__ __forceinline__ int swz(int row, int kb) {
  return (row << 6) + ((((kb >> 4) ^ ((row >> 1) & 3)) << 4) | (kb & 15));
}

// XCD-bijective block swizzle (requires gridDim.x % 8 == 0).
__device__ __forceinline__ int xcd_swz(int bid, int nwg) {
  int cpx = nwg >> 3;
  return (bid & 7) * cpx + (bid >> 3);
}

#define GLD(src, dst)                                                          \
  __builtin_amdgcn_global_load_lds(                                            \
      (const __attribute__((address_space(1))) void*)(src),                    \
      (__attribute__((address_space(3))) void*)(dst), 16, 0, 0)

// ---------------- L1/L3 kernel: A direct global->reg, B via LDS, dbuf -------
// MODE 0: hi/lo inputs -> Chi+Clo (split-f16 precise, 3 MFMA/frag).
// MODE 2: hi-only inputs -> f32 C.
// A-fragment is lane-addressable in row-major global memory (lane reads 16B at
// row=..+(lane&15), k=(lane>>4)*8); each 64B A-line is fully consumed in one
// K-step and shared by the 2 column-waves -> L1-served. This removes A from
// LDS: LDS traffic/step (MODE0) = B reads 128KB + writes 16KB < MFMA time.
// Hazards (r8-proven): dbuf, per step {vmcnt(0); barrier; STAGE_B(next);
// LOAD_A(next)->regs; compute}. All LDS writes are GLD; A-reg deps are
// compiler-tracked; vmcnt(0)+barrier publishes B stages.
template <int MODE>
__global__ __launch_bounds__(1024, 4)
void gemm_tri(const _Float16* __restrict__ Ahi, const _Float16* __restrict__ Alo,
              const _Float16* __restrict__ Bhi, const _Float16* __restrict__ Blo,
              const float* __restrict__ bias,
              _Float16* __restrict__ Chi, _Float16* __restrict__ Clo,
              float* __restrict__ Cf, int M, int N, int K, int nbx) {
  constexpr bool LO = (MODE < 2);
  constexpr int BLO = 8192;
  constexpr int STG = LO ? 16384 : 8192;
  __shared__ char lds[2 * STG];

  const int tid = threadIdx.x;
  const int sid = xcd_swz(blockIdx.x, gridDim.x);
  const int m0 = (sid / nbx) * BM;
  const int n0 = (sid % nbx) * BN;
  const int wave = tid >> 6, lane = tid & 63;
  const int wm = wave >> 1, wn = wave & 1;   // 8x2 wave grid; wave tile 32x64
  const int NK = K / BK;

  f32x4 acc_hi[2][4], acc_mid[2][4];
#pragma unroll
  for (int m = 0; m < 2; m++)
#pragma unroll
    for (int n = 0; n < 4; n++) { acc_hi[m][n] = (f32x4)0.0f; acc_mid[m][n] = (f32x4)0.0f; }

  // B staging source (pre-swizzled; 512 threads cover 128 rows x 4 slots).
  const int brow = (tid & 511) >> 2;
  const int kx = (tid & 3) ^ ((brow >> 1) & 3);
  const size_t boff = (size_t)(n0 + brow) * K + kx * 8;

  // A global lane base: row = m0 + wm*32 + mi*16 + (lane&15), k = ks*32+(lane>>4)*8
  const int rl = lane & 15;
  const int kb = (lane >> 4) << 4;
  const _Float16* agp = Ahi + (size_t)(m0 + wm * 32 + rl) * K + ((lane >> 4) << 3);
  const _Float16* agl = LO ? Alo + (size_t)(m0 + wm * 32 + rl) * K + ((lane >> 4) << 3)
                           : nullptr;
  const size_t aRowStride = (size_t)16 * K;   // mi step

  int bswz[4];
#pragma unroll
  for (int i = 0; i < 4; i++) bswz[i] = swz(wn * 64 + i * 16 + rl, kb);

  auto STAGE = [&](int buf, int ks) {
    char* sb = lds + buf * STG;
    const size_t ko = (size_t)ks * BK;
    if constexpr (LO) {
      if (wave < 8) GLD(Bhi + boff + ko, sb + (wave << 10));
      else          GLD(Blo + boff + ko, sb + BLO + ((wave - 8) << 10));
    } else {
      if (wave < 8) GLD(Bhi + boff + ko, sb + (wave << 10));
    }
  };

  auto LOAD_A = [&](half8 (&ah)[2], half8 (&al)[2], int ks) {
    const size_t ko = (size_t)ks * BK;
#pragma unroll
    for (int mi = 0; mi < 2; mi++) {
      ah[mi] = *(const half8*)(agp + ko + mi * aRowStride);
      if constexpr (LO) al[mi] = *(const half8*)(agl + ko + mi * aRowStride);
    }
  };

  auto COMPUTE = [&](int buf, half8 (&ah)[2], half8 (&al)[2]) {
    char* base = lds + buf * STG;
    half8 bh[4], bl[4];
#pragma unroll
    for (int ni = 0; ni < 4; ni++) {
      bh[ni] = *(half8*)(base + bswz[ni]);
      if constexpr (LO) bl[ni] = *(half8*)(base + BLO + bswz[ni]);
    }
    __builtin_amdgcn_s_setprio(1);
#pragma unroll
    for (int mi = 0; mi < 2; mi++)
#pragma unroll
      for (int ni = 0; ni < 4; ni++) {
        acc_hi[mi][ni] = __builtin_amdgcn_mfma_f32_16x16x32_f16(ah[mi], bh[ni], acc_hi[mi][ni], 0, 0, 0);
        if constexpr (LO) {
          acc_mid[mi][ni] = __builtin_amdgcn_mfma_f32_16x16x32_f16(ah[mi], bl[ni], acc_mid[mi][ni], 0, 0, 0);
          acc_mid[mi][ni] = __builtin_amdgcn_mfma_f32_16x16x32_f16(al[mi], bh[ni], acc_mid[mi][ni], 0, 0, 0);
        }
      }
    __builtin_amdgcn_s_setprio(0);
  };

  half8 ahA[2], alA[2], ahB[2], alB[2];
  LOAD_A(ahA, alA, 0);
  STAGE(0, 0);
  for (int ks = 0; ks < NK; ks += 2) {
    asm volatile("s_waitcnt vmcnt(0)" ::: "memory");
    __builtin_amdgcn_s_barrier();
    if (ks + 1 < NK) { STAGE(1, ks + 1); LOAD_A(ahB, alB, ks + 1); }
    COMPUTE(0, ahA, alA);
    asm volatile("s_waitcnt vmcnt(0)" ::: "memory");
    __builtin_amdgcn_s_barrier();
    if (ks + 2 < NK) { STAGE(0, ks + 2); LOAD_A(ahA, alA, ks + 2); }
    COMPUTE(1, ahB, alB);
  }

  const int col_l = lane & 15, rgrp = lane >> 4;
#pragma unroll
  for (int ni = 0; ni < 4; ni++) {
    int col = n0 + wn * 64 + ni * 16 + col_l;
    float bv = bias[col];
#pragma unroll
    for (int mi = 0; mi < 2; mi++) {
      int rowb = m0 + wm * 32 + mi * 16 + rgrp * 4;
#pragma unroll
      for (int i = 0; i < 4; i++) {
        size_t idx = (size_t)(rowb + i) * N + col;
        if constexpr (MODE == 2) {
          Cf[idx] = acc_hi[mi][ni][i] + bv;
        } else {
          float c = acc_hi[mi][ni][i] + acc_mid[mi][ni][i] * (1.0f / 2048.0f) + bv;
          _Float16 hh = (_Float16)c;
          Chi[idx] = hh;
          if constexpr (MODE == 0) Clo[idx] = (_Float16)((c - (float)hh) * 2048.0f);
        }
      }
    }
  }
}

// ---------------- L2 kernel: hi-only, 256x256, A global->reg, B LDS ---------
// BK=64 epochs, dbuf. LDS/epoch = B reads 128KB + writes 32KB (~1880cy) <
// MFMA 2484cy -> MFMA-bound.
#define SQ_BUF 32768   // 2 halves x 16KB (B only)

__global__ __launch_bounds__(1024, 4)
void gemm_sq(const _Float16* __restrict__ Ahi, const _Float16* __restrict__ Bhi,
             const float* __restrict__ bias, _Float16* __restrict__ Chi,
             int M, int N, int K, int nbx) {
  __shared__ char lds[2 * SQ_BUF];
  const int tid = threadIdx.x;
  const int sid = xcd_swz(blockIdx.x, gridDim.x);
  const int m0 = (sid / nbx) * 256;
  const int n0 = (sid % nbx) * 256;
  const int wave = tid >> 6, lane = tid & 63;
  const int wm = wave >> 2, wn = wave & 3;   // 4x4 wave grid; wave tile 64x64
  const int NE = K / 64;

  f32x4 acc[4][4];
#pragma unroll
  for (int m = 0; m < 4; m++)
#pragma unroll
    for (int n = 0; n < 4; n++) acc[m][n] = (f32x4)0.0f;

  const int srow = tid >> 2;                  // 0..255 (B rows)
  const int kx = (tid & 3) ^ ((srow >> 1) & 3);
  const size_t boff = (size_t)(n0 + srow) * K + kx * 8;

  const int rl = lane & 15;
  const int kb = (lane >> 4) << 4;
  const _Float16* agp = Ahi + (size_t)(m0 + wm * 64 + rl) * K + ((lane >> 4) << 3);
  const size_t aRowStride = (size_t)16 * K;

  int bswz[4];
#pragma unroll
  for (int i = 0; i < 4; i++) bswz[i] = swz(wn * 64 + i * 16 + rl, kb);

  auto STAGE_B = [&](int buf, int half, int ks) {
    char* sb = lds + buf * SQ_BUF + half * 16384 + (wave << 10);
    GLD(Bhi + boff + (size_t)ks * BK, sb);
  };
  auto LOAD_A = [&](half8 (&a)[4], int ks) {
    const size_t ko = (size_t)ks * BK;
#pragma unroll
    for (int mi = 0; mi < 4; mi++)
      a[mi] = *(const half8*)(agp + ko + mi * aRowStride);
  };
  auto COMPUTE_H = [&](int buf, int half, half8 (&a)[4]) {
    char* base = lds + buf * SQ_BUF + half * 16384;
    half8 bh[4];
#pragma unroll
    for (int i = 0; i < 4; i++) bh[i] = *(half8*)(base + bswz[i]);
    __builtin_amdgcn_s_setprio(1);
#pragma unroll
    for (int mi = 0; mi < 4; mi++)
#pragma unroll
      for (int ni = 0; ni < 4; ni++)
        acc[mi][ni] = __builtin_amdgcn_mfma_f32_16x16x32_f16(a[mi], bh[ni], acc[mi][ni], 0, 0, 0);
    __builtin_amdgcn_s_setprio(0);
  };

  half8 a0[4], a1[4];
  LOAD_A(a0, 0);
  STAGE_B(0, 0, 0);
  STAGE_B(0, 1, 1);
  int buf = 0;
  for (int e = 0; e < NE; ++e) {
    asm volatile("s_waitcnt vmcnt(0)" ::: "memory");
    __builtin_amdgcn_s_barrier();
    if (e + 1 < NE) STAGE_B(buf ^ 1, 0, 2 * e + 2);
    LOAD_A(a1, 2 * e + 1);
    COMPUTE_H(buf, 0, a0);
    if (e + 1 < NE) { STAGE_B(buf ^ 1, 1, 2 * e + 3); LOAD_A(a0, 2 * e + 2); }
    COMPUTE_H(buf, 1, a1);
    buf ^= 1;
  }

  const int col_l = lane & 15, rgrp = lane >> 4;
#pragma unroll
  for (int ni = 0; ni < 4; ni++) {
    int col = n0 + wn * 64 + ni * 16 + col_l;
    float bv = bias[col];
#pragma unroll
    for (int mi = 0; mi < 4; mi++) {
      int rowb = m0 + wm * 64 + mi * 16 + rgrp * 4;
#pragma unroll
      for (int i = 0; i < 4; i++)
        Chi[(size_t)(rowb + i) * N + col] = (_Float16)(acc[mi][ni][i] + bv);
    }
  }
}

// Fused split: 4 segments, f32 -> hi f16 (+ lo f16 x2048 where dst given).
__global__ __launch_bounds__(256)
void split4_kernel(const float* __restrict__ s0, _Float16* __restrict__ h0,
                   _Float16* __restrict__ l0, size_t n0,
                   const float* __restrict__ s1, _Float16* __restrict__ h1,
                   _Float16* __restrict__ l1, size_t n1,
                   const float* __restrict__ s2, _Float16* __restrict__ h2,
                   size_t n2,
                   const float* __restrict__ s3, _Float16* __restrict__ h3,
                   size_t n3) {
  const size_t tot = n0 + n1 + n2 + n3;   // in float4 units
  size_t i = (size_t)blockIdx.x * 256 + threadIdx.x;
  const size_t stride = (size_t)gridDim.x * 256;
  for (; i < tot; i += stride) {
    const float* src; _Float16* hi; _Float16* lo; size_t j = i;
    if (j < n0) { src = s0; hi = h0; lo = l0; }
    else if ((j -= n0) < n1) { src = s1; hi = h1; lo = l1; }
    else if ((j -= n1) < n2) { src = s2; hi = h2; lo = nullptr; }
    else { j -= n2; src = s3; hi = h3; lo = nullptr; }
    float4 q = ((const float4*)src)[j];
    float a[4] = {q.x, q.y, q.z, q.w};
    half4 h, l;
#pragma unroll
    for (int k = 0; k < 4; ++k) {
      _Float16 hh = (_Float16)a[k];
      h[k] = hh;
      l[k] = (_Float16)((a[k] - (float)hh) * 2048.0f);
    }
    ((half4*)hi)[j] = h;
    if (lo) ((half4*)lo)[j] = l;
  }
}

// One block per row of Z. MASK-RELEVANCE-FILTERED fp64 recheck (r10-proven).
__global__ __launch_bounds__(256)
void sda_fix(_Float16* __restrict__ Zhi, _Float16* __restrict__ Zlo,
             const float* __restrict__ Af,
             const _Float16* __restrict__ Ahi, const _Float16* __restrict__ Alo,
             const float* __restrict__ W, const float* __restrict__ bias,
             int H, int K, float TAU) {
  __shared__ int sPos[4], sNeg[4];
  __shared__ int nFix;
  __shared__ int fixIdx[96];
  __shared__ double sRed[4];
  __shared__ float sVal;
  const int row = blockIdx.x;
  _Float16* zh = Zhi + (size_t)row * H;
  _Float16* zl = Zlo ? Zlo + (size_t)row * H : nullptr;
  const int t = threadIdx.x;

  if (t == 0) nFix = 0;
  __syncthreads();

  float v[16];
  {
    half8 a0 = ((const half8*)zh)[t * 2], a1 = ((const half8*)zh)[t * 2 + 1];
    if (zl) {
      half8 b0 = ((const half8*)zl)[t * 2], b1 = ((const half8*)zl)[t * 2 + 1];
#pragma unroll
      for (int e = 0; e < 8; ++e) {
        v[e]     = (float)a0[e] + (float)b0[e] * (1.0f / 2048.0f);
        v[8 + e] = (float)a1[e] + (float)b1[e] * (1.0f / 2048.0f);
      }
    } else {
#pragma unroll
      for (int e = 0; e < 8; ++e) { v[e] = (float)a0[e]; v[8 + e] = (float)a1[e]; }
    }
  }

  bool cposa[4], pposa[4], cnega[4], pnega[4];
  int firstCpos = 0x7fffffff, firstCneg = 0x7fffffff;
#pragma unroll
  for (int j = 0; j < 4; ++j) {
    float g0 = v[j*4], g1 = v[j*4+1], g2 = v[j*4+2], g3 = v[j*4+3];
    cposa[j] = (g0 >  TAU) & (g1 >  TAU) & (g2 >  TAU) & (g3 >  TAU);
    pposa[j] = (g0 > -TAU) & (g1 > -TAU) & (g2 > -TAU) & (g3 > -TAU);
    cnega[j] = (g0 < -TAU) & (g1 < -TAU) & (g2 < -TAU) & (g3 < -TAU);
    pnega[j] = (g0 <  TAU) & (g1 <  TAU) & (g2 <  TAU) & (g3 <  TAU);
    int gi = (t << 2) + j;
    if (cposa[j] && gi < firstCpos) firstCpos = gi;
    if (cnega[j] && gi < firstCneg) firstCneg = gi;
  }
#pragma unroll
  for (int off = 32; off; off >>= 1) {
    firstCpos = min(firstCpos, __shfl_xor(firstCpos, off));
    firstCneg = min(firstCneg, __shfl_xor(firstCneg, off));
  }
  if ((t & 63) == 0) { sPos[t >> 6] = firstCpos; sNeg[t >> 6] = firstCneg; }
  __syncthreads();
  firstCpos = min(min(sPos[0], sPos[1]), min(sPos[2], sPos[3]));
  firstCneg = min(min(sNeg[0], sNeg[1]), min(sNeg[2], sNeg[3]));
  __syncthreads();

#pragma unroll
  for (int j = 0; j < 4; ++j) {
    int gi = (t << 2) + j;
    bool qual = (pposa[j] && !cposa[j] && gi <= firstCpos) ||
                (pnega[j] && !cnega[j] && gi <= firstCneg);
    if (qual) {
#pragma unroll
      for (int e = 0; e < 4; ++e) {
        if (fabsf(v[j*4+e]) < TAU) {
          int slot = atomicAdd(&nFix, 1);
          if (slot < 96) fixIdx[slot] = gi * 4 + e;
        }
      }
    }
  }
  __syncthreads();
  const int nf = min(nFix, 96);
  unsigned fixmask = 0;
  for (int i = 0; i < nf; ++i) {
    const int col = fixIdx[i];
    double s = 0.0;
    const float* wr = W + (size_t)col * K;
    if (Af) {
      const float* ar = Af + (size_t)row * K;
      for (int k = t; k < K; k += 256) s += (double)ar[k] * (double)wr[k];
    } else {
      const _Float16* ah = Ahi + (size_t)row * K;
      const _Float16* al = Alo + (size_t)row * K;
      for (int k = t; k < K; k += 256)
        s += ((double)(float)ah[k] + (double)(float)al[k] * (1.0 / 2048.0)) * (double)wr[k];
    }
#pragma unroll
    for (int off = 32; off; off >>= 1) s += __shfl_xor(s, off);
    if ((t & 63) == 0) sRed[t >> 6] = s;
    __syncthreads();
    if (t == 0)
      sVal = (float)(sRed[0] + sRed[1] + sRed[2] + sRed[3] + (double)bias[col]);
    __syncthreads();
    if ((col >> 4) == t) { v[col & 15] = sVal; fixmask |= 1u << (col & 15); }
    __syncthreads();
  }

  int fp = 0x7fffffff, fn = 0x7fffffff;
#pragma unroll
  for (int j = 0; j < 4; ++j) {
    bool ap = (v[j*4+0] > 0.f) & (v[j*4+1] > 0.f) & (v[j*4+2] > 0.f) & (v[j*4+3] > 0.f);
    bool an = (v[j*4+0] < 0.f) & (v[j*4+1] < 0.f) & (v[j*4+2] < 0.f) & (v[j*4+3] < 0.f);
    int g = (t << 2) + j;
    if (ap && g < fp) fp = g;
    if (an && g < fn) fn = g;
  }
#pragma unroll
  for (int off = 32; off; off >>= 1) {
    fp = min(fp, __shfl_xor(fp, off));
    fn = min(fn, __shfl_xor(fn, off));
  }
  if ((t & 63) == 0) { sPos[t >> 6] = fp; sNeg[t >> 6] = fn; }
  __syncthreads();
  fp = min(min(sPos[0], sPos[1]), min(sPos[2], sPos[3]));
  fn = min(min(sNeg[0], sNeg[1]), min(sNeg[2], sNeg[3]));
  const int act   = (fp == 0x7fffffff) ? -1 : fp;
  const int inact = (fn == 0x7fffffff) ? -1 : fn;

  unsigned chg = fixmask;
#pragma unroll
  for (int j = 0; j < 4; ++j) {
    int g = (t << 2) + j;
    if (g == act) {
      v[j*4+0] *= 2.f; v[j*4+1] *= 2.f; v[j*4+2] *= 2.f; v[j*4+3] *= 2.f;
      chg |= 0xFu << (j * 4);
    } else if (g == inact) {
      v[j*4+0] = v[j*4+1] = v[j*4+2] = v[j*4+3] = 0.f;
      chg |= 0xFu << (j * 4);
    }
  }
  while (chg) {
    int e = __ffs(chg) - 1; chg &= chg - 1;
    float val = v[e];
    _Float16 hh = (_Float16)val;
    zh[(t << 4) + e] = hh;
    if (zl) zl[(t << 4) + e] = (_Float16)((val - (float)hh) * 2048.0f);
  }
}

extern "C" void kernel_launch(void* const* d_in, const int* in_sizes, int n_in,
                              void* d_out, int out_size, void* d_ws, size_t ws_size,
                              hipStream_t stream) {
  const float* x  = (const float*)d_in[0];
  const float* W1 = (const float*)d_in[1];
  const float* b1 = (const float*)d_in[2];
  const float* W2 = (const float*)d_in[3];
  const float* b2 = (const float*)d_in[4];
  const float* W3 = (const float*)d_in[5];
  const float* b3 = (const float*)d_in[6];
  float* out = (float*)d_out;

  const int M = 8192, H = 4096, DIN = 1024, DOUT = 1024;

  // Scratch: 256 MiB, time-sliced aliasing (r11-proven layout).
  char* w = (char*)d_ws;
  _Float16* Z1hi = (_Float16*)(w + 0);
  _Float16* Z1lo = (_Float16*)(w + ((size_t)64 << 20));
  _Float16* Z2hi = (_Float16*)(w + ((size_t)128 << 20));
  _Float16* W2hi = (_Float16*)(w + ((size_t)192 << 20));
  // aliases (dead before their region's long-term owner is written)
  _Float16* xhi  = (_Float16*)(w + ((size_t)128 << 20));
  _Float16* xlo  = (_Float16*)(w + ((size_t)144 << 20));
  _Float16* W1hi = (_Float16*)(w + ((size_t)160 << 20));
  _Float16* W1lo = (_Float16*)(w + ((size_t)168 << 20));
  _Float16* W3hi = (_Float16*)(w + ((size_t)224 << 20));

  split4_kernel<<<2048, 256, 0, stream>>>(
      x,  xhi,  xlo,  (size_t)(M * DIN) >> 2,
      W1, W1hi, W1lo, (size_t)(H * DIN) >> 2,
      W2, W2hi,       (size_t)((size_t)H * H) >> 2,
      W3, W3hi,       (size_t)(DOUT * H) >> 2);

  // L1: Z1 = x @ W1^T + b1   (K=1024) — split-f16 precise, hi/lo out
  gemm_tri<0><<<dim3((H / BN) * (M / BM)), dim3(1024), 0, stream>>>(
      xhi, xlo, W1hi, W1lo, b1, Z1hi, Z1lo, (float*)nullptr, M, H, DIN, H / BN);
  sda_fix<<<M, 256, 0, stream>>>(Z1hi, Z1lo, x, (const _Float16*)nullptr,
                                 (const _Float16*)nullptr, W1, b1, H, DIN, 1e-4f);
  // L2: Z2 = Z1 @ W2^T + b2  (K=4096) — hi-only, A from global, B LDS
  gemm_sq<<<dim3((H / 256) * (M / 256)), dim3(1024), 0, stream>>>(
      Z1hi, W2hi, b2, Z2hi, M, H, H, H / 256);
  sda_fix<<<M, 256, 0, stream>>>(Z2hi, (_Float16*)nullptr, (const float*)nullptr,
                                 Z1hi, Z1lo, W2, b2, H, H, 5e-3f);
  // L3: out = Z2 @ W3^T + b3 (N=1024) — hi-only
  gemm_tri<2><<<dim3((DOUT / BN) * (M / BM)), dim3(1024), 0, stream>>>(
      Z2hi, (const _Float16*)nullptr, W3hi, (const _Float16*)nullptr, b3,
      (_Float16*)nullptr, (_Float16*)nullptr, out, M, DOUT, H, DOUT / BN);
}

// Round 13
// 613.377 us; speedup vs baseline: 2.9766x; 2.9766x over previous
//
#include <hip/hip_runtime.h>
#include <stdint.h>

using half8 = __attribute__((ext_vector_type(8))) _Float16;
using half4 = __attribute__((ext_vector_type(4))) _Float16;
using f32x4 = __attribute__((ext_vector_type(4))) float;

#define BM 256
#define BN 128
#define BK 32

// Bank-conflict-free layout: granule (row, k8) at byte row*64 + (k8 ^ ((row>>1)&3))*16.
// Read side uses swz() (16-row column reads -> 2-way aliasing = free);
// GLD staging realizes it via pre-swizzled global source addresses
// (LDS dest must be linear: wave-uniform base + lane*16).
__device__ __forceinline__ int swz(int row, int kb) {
  return (row << 6) + ((((kb >> 4) ^ ((row >> 1) & 3)) << 4) | (kb & 15));
}

// XCD-bijective block swizzle (requires gridDim.x % 8 == 0): XCD k owns a
// contiguous chunk of logical tile ids -> neighboring tiles share L2.
__device__ __forceinline__ int xcd_swz(int bid, int nwg) {
  int cpx = nwg >> 3;
  return (bid & 7) * cpx + (bid >> 3);
}

#define GLD(src, dst)                                                          \
  __builtin_amdgcn_global_load_lds(                                            \
      (const __attribute__((address_space(1))) void*)(src),                    \
      (__attribute__((address_space(3))) void*)(dst), 16, 0, 0)

// ---------------- L1/L3 kernel (r7-proven): tri-buffer counted-vmcnt --------
// MODE 0: hi/lo inputs -> Chi+Clo (split-f16 precise, 3 MFMA/frag).
// MODE 2: hi-only inputs -> f32 C.
// Fragment registers live only inside COMPUTE (no persistent A/B reg buffers)
// -> fits the 128-reg unified budget at 4 waves/SIMD (r12 lesson: persistent
// per-step reg buffers spill to scratch and cost 3x).
template <int MODE>
__global__ __launch_bounds__(1024, 4)
void gemm_tri(const _Float16* __restrict__ Ahi, const _Float16* __restrict__ Alo,
              const _Float16* __restrict__ Bhi, const _Float16* __restrict__ Blo,
              const float* __restrict__ bias,
              _Float16* __restrict__ Chi, _Float16* __restrict__ Clo,
              float* __restrict__ Cf, int M, int N, int K, int nbx) {
  constexpr bool LO = (MODE < 2);
  constexpr int AHI = 0;
  constexpr int ALO = 16384;
  constexpr int BHI = LO ? 32768 : 16384;
  constexpr int BLO = 40960;
  constexpr int STG = LO ? 49152 : 24576;
  __shared__ char lds[3 * STG];

  const int tid = threadIdx.x;
  const int sid = xcd_swz(blockIdx.x, gridDim.x);
  const int m0 = (sid / nbx) * BM;
  const int n0 = (sid % nbx) * BN;
  const int wave = tid >> 6, lane = tid & 63;
  const int wm = wave >> 1, wn = wave & 1;   // 8x2 wave grid; wave tile 32x64
  const int NK = K / BK;

  f32x4 acc_hi[2][4], acc_mid[2][4];
#pragma unroll
  for (int m = 0; m < 2; m++)
#pragma unroll
    for (int n = 0; n < 4; n++) { acc_hi[m][n] = (f32x4)0.0f; acc_mid[m][n] = (f32x4)0.0f; }

  const int srow = tid >> 2;                  // 0..255 (A rows)
  const int kx = (tid & 3) ^ ((srow >> 1) & 3);
  const size_t aoff = (size_t)(m0 + srow) * K + kx * 8;
  const int brow = (tid & 511) >> 2;          // 0..127 (B rows)
  const size_t boff = (size_t)(n0 + brow) * K + kx * 8;

  auto STAGE = [&](int buf, int ks) {
    char* sb = lds + buf * STG;
    const size_t ko = (size_t)ks * BK;
    GLD(Ahi + aoff + ko, sb + AHI + (wave << 10));
    if constexpr (LO) {
      GLD(Alo + aoff + ko, sb + ALO + (wave << 10));
      if (wave < 8) GLD(Bhi + boff + ko, sb + BHI + (wave << 10));
      else          GLD(Blo + boff + ko, sb + BLO + ((wave - 8) << 10));
    } else {
      if (wave < 8) GLD(Bhi + boff + ko, sb + BHI + (wave << 10));
    }
  };

  auto COMPUTE = [&](int buf) {
    char* base = lds + buf * STG;
    const int kb = (lane >> 4) << 4;
    const int rl = lane & 15;
    half8 ah[2], al[2], bh[4], bl[4];
#pragma unroll
    for (int mi = 0; mi < 2; mi++) {
      int off = swz(wm * 32 + mi * 16 + rl, kb);
      ah[mi] = *(half8*)(base + AHI + off);
      if constexpr (LO) al[mi] = *(half8*)(base + ALO + off);
    }
#pragma unroll
    for (int ni = 0; ni < 4; ni++) {
      int off = swz(wn * 64 + ni * 16 + rl, kb);
      bh[ni] = *(half8*)(base + BHI + off);
      if constexpr (LO) bl[ni] = *(half8*)(base + BLO + off);
    }
    __builtin_amdgcn_s_setprio(1);
#pragma unroll
    for (int mi = 0; mi < 2; mi++)
#pragma unroll
      for (int ni = 0; ni < 4; ni++) {
        acc_hi[mi][ni] = __builtin_amdgcn_mfma_f32_16x16x32_f16(ah[mi], bh[ni], acc_hi[mi][ni], 0, 0, 0);
        if constexpr (LO) {
          acc_mid[mi][ni] = __builtin_amdgcn_mfma_f32_16x16x32_f16(ah[mi], bl[ni], acc_mid[mi][ni], 0, 0, 0);
          acc_mid[mi][ni] = __builtin_amdgcn_mfma_f32_16x16x32_f16(al[mi], bh[ni], acc_mid[mi][ni], 0, 0, 0);
        }
      }
    __builtin_amdgcn_s_setprio(0);
  };

  STAGE(0, 0);
  STAGE(1, 1);
  int cur = 0;
  for (int ks = 0; ks < NK; ++ks) {
    if (ks + 1 < NK) {
      if constexpr (LO) {
        asm volatile("s_waitcnt vmcnt(3)" ::: "memory");
      } else {
        if (wave < 8) asm volatile("s_waitcnt vmcnt(2)" ::: "memory");
        else          asm volatile("s_waitcnt vmcnt(1)" ::: "memory");
      }
    } else {
      asm volatile("s_waitcnt vmcnt(0)" ::: "memory");
    }
    __builtin_amdgcn_s_barrier();
    if (ks + 2 < NK) {
      int nbuf = cur + 2; if (nbuf >= 3) nbuf -= 3;
      STAGE(nbuf, ks + 2);
    }
    COMPUTE(cur);
    if (++cur == 3) cur = 0;
  }

  const int col_l = lane & 15, rgrp = lane >> 4;
#pragma unroll
  for (int ni = 0; ni < 4; ni++) {
    int col = n0 + wn * 64 + ni * 16 + col_l;
    float bv = bias[col];
#pragma unroll
    for (int mi = 0; mi < 2; mi++) {
      int rowb = m0 + wm * 32 + mi * 16 + rgrp * 4;
#pragma unroll
      for (int i = 0; i < 4; i++) {
        size_t idx = (size_t)(rowb + i) * N + col;
        if constexpr (MODE == 2) {
          Cf[idx] = acc_hi[mi][ni][i] + bv;
        } else {
          float c = acc_hi[mi][ni][i] + acc_mid[mi][ni][i] * (1.0f / 2048.0f) + bv;
          _Float16 hh = (_Float16)c;
          Chi[idx] = hh;
          if constexpr (MODE == 0) Clo[idx] = (_Float16)((c - (float)hh) * 2048.0f);
        }
      }
    }
  }
}

// ---------------- L2 kernel: hi-only f16, 256x256 tile, BK=64 EPOCHS --------
// Two K-steps per barrier: {vmcnt(0); barrier; stage-half0(next);
// compute-half0; stage-half1(next); compute-half1}. Double buffer 2x64KB.
// Hazards: own-vmcnt + barrier publish all of buf's stages (issued last
// epoch); post-barrier stages target buf^1, read only next epoch (WAR-safe
// via barrier). MFMA order per accumulator identical to per-step version.
#define SQ_BUF 65536

__global__ __launch_bounds__(1024, 4)
void gemm_sq(const _Float16* __restrict__ Ahi, const _Float16* __restrict__ Bhi,
             const float* __restrict__ bias, _Float16* __restrict__ Chi,
             int M, int N, int K, int nbx) {
  __shared__ char lds[2 * SQ_BUF];
  const int tid = threadIdx.x;
  const int sid = xcd_swz(blockIdx.x, gridDim.x);
  const int m0 = (sid / nbx) * 256;
  const int n0 = (sid % nbx) * 256;
  const int wave = tid >> 6, lane = tid & 63;
  const int wm = wave >> 2, wn = wave & 3;   // 4x4 wave grid; wave tile 64x64
  const int NE = K / 64;                     // epochs of 2 K-steps

  f32x4 acc[4][4];
#pragma unroll
  for (int m = 0; m < 4; m++)
#pragma unroll
    for (int n = 0; n < 4; n++) acc[m][n] = (f32x4)0.0f;

  const int srow = tid >> 2;                  // 0..255
  const int kx = (tid & 3) ^ ((srow >> 1) & 3);
  const size_t aoff = (size_t)(m0 + srow) * K + kx * 8;
  const size_t boff = (size_t)(n0 + srow) * K + kx * 8;

  const int kb = (lane >> 4) << 4;
  const int rl = lane & 15;
  int aswz[4], bswz[4];
#pragma unroll
  for (int i = 0; i < 4; i++) {
    aswz[i] = swz(wm * 64 + i * 16 + rl, kb);
    bswz[i] = 16384 + swz(wn * 64 + i * 16 + rl, kb);
  }

  auto STAGE_H = [&](int buf, int half, int ks) {
    char* sb = lds + buf * SQ_BUF + half * 32768 + (wave << 10);
    const size_t ko = (size_t)ks * BK;
    GLD(Ahi + aoff + ko, sb);
    GLD(Bhi + boff + ko, sb + 16384);
  };

  auto COMPUTE_H = [&](int buf, int half) {
    char* base = lds + buf * SQ_BUF + half * 32768;
    half8 ah[4], bh[4];
#pragma unroll
    for (int i = 0; i < 4; i++) {
      ah[i] = *(half8*)(base + aswz[i]);
      bh[i] = *(half8*)(base + bswz[i]);
    }
    __builtin_amdgcn_s_setprio(1);
#pragma unroll
    for (int mi = 0; mi < 4; mi++)
#pragma unroll
      for (int ni = 0; ni < 4; ni++)
        acc[mi][ni] = __builtin_amdgcn_mfma_f32_16x16x32_f16(ah[mi], bh[ni], acc[mi][ni], 0, 0, 0);
    __builtin_amdgcn_s_setprio(0);
  };

  STAGE_H(0, 0, 0);
  STAGE_H(0, 1, 1);
  int buf = 0;
  for (int e = 0; e < NE; ++e) {
    asm volatile("s_waitcnt vmcnt(0)" ::: "memory");
    __builtin_amdgcn_s_barrier();
    if (e + 1 < NE) STAGE_H(buf ^ 1, 0, 2 * e + 2);
    COMPUTE_H(buf, 0);
    if (e + 1 < NE) STAGE_H(buf ^ 1, 1, 2 * e + 3);
    COMPUTE_H(buf, 1);
    buf ^= 1;
  }

  const int col_l = lane & 15, rgrp = lane >> 4;
#pragma unroll
  for (int ni = 0; ni < 4; ni++) {
    int col = n0 + wn * 64 + ni * 16 + col_l;
    float bv = bias[col];
#pragma unroll
    for (int mi = 0; mi < 4; mi++) {
      int rowb = m0 + wm * 64 + mi * 16 + rgrp * 4;
#pragma unroll
      for (int i = 0; i < 4; i++)
        Chi[(size_t)(rowb + i) * N + col] = (_Float16)(acc[mi][ni][i] + bv);
    }
  }
}

// Fused split: 4 segments, f32 -> hi f16 (+ lo f16 x2048 where dst given).
__global__ __launch_bounds__(256)
void split4_kernel(const float* __restrict__ s0, _Float16* __restrict__ h0,
                   _Float16* __restrict__ l0, size_t n0,
                   const float* __restrict__ s1, _Float16* __restrict__ h1,
                   _Float16* __restrict__ l1, size_t n1,
                   const float* __restrict__ s2, _Float16* __restrict__ h2,
                   size_t n2,
                   const float* __restrict__ s3, _Float16* __restrict__ h3,
                   size_t n3) {
  const size_t tot = n0 + n1 + n2 + n3;   // in float4 units
  size_t i = (size_t)blockIdx.x * 256 + threadIdx.x;
  const size_t stride = (size_t)gridDim.x * 256;
  for (; i < tot; i += stride) {
    const float* src; _Float16* hi; _Float16* lo; size_t j = i;
    if (j < n0) { src = s0; hi = h0; lo = l0; }
    else if ((j -= n0) < n1) { src = s1; hi = h1; lo = l1; }
    else if ((j -= n1) < n2) { src = s2; hi = h2; lo = nullptr; }
    else { j -= n2; src = s3; hi = h3; lo = nullptr; }
    float4 q = ((const float4*)src)[j];
    float a[4] = {q.x, q.y, q.z, q.w};
    half4 h, l;
#pragma unroll
    for (int k = 0; k < 4; ++k) {
      _Float16 hh = (_Float16)a[k];
      h[k] = hh;
      l[k] = (_Float16)((a[k] - (float)hh) * 2048.0f);
    }
    ((half4*)hi)[j] = h;
    if (lo) ((half4*)lo)[j] = l;
  }
}

// One block per row of Z. MASK-RELEVANCE-FILTERED fp64 recheck (r10-proven):
// recheck a borderline elem only if its group could alter the first all-pos /
// all-neg selection. Exact for masks; non-relevant borderline values keep the
// GEMM value (err <= ~1.6e-3, harmless vs the 0.0216 threshold).
__global__ __launch_bounds__(256)
void sda_fix(_Float16* __restrict__ Zhi, _Float16* __restrict__ Zlo,
             const float* __restrict__ Af,
             const _Float16* __restrict__ Ahi, const _Float16* __restrict__ Alo,
             const float* __restrict__ W, const float* __restrict__ bias,
             int H, int K, float TAU) {
  __shared__ int sPos[4], sNeg[4];
  __shared__ int nFix;
  __shared__ int fixIdx[96];
  __shared__ double sRed[4];
  __shared__ float sVal;
  const int row = blockIdx.x;
  _Float16* zh = Zhi + (size_t)row * H;
  _Float16* zl = Zlo ? Zlo + (size_t)row * H : nullptr;
  const int t = threadIdx.x;

  if (t == 0) nFix = 0;
  __syncthreads();

  float v[16];
  {
    half8 a0 = ((const half8*)zh)[t * 2], a1 = ((const half8*)zh)[t * 2 + 1];
    if (zl) {
      half8 b0 = ((const half8*)zl)[t * 2], b1 = ((const half8*)zl)[t * 2 + 1];
#pragma unroll
      for (int e = 0; e < 8; ++e) {
        v[e]     = (float)a0[e] + (float)b0[e] * (1.0f / 2048.0f);
        v[8 + e] = (float)a1[e] + (float)b1[e] * (1.0f / 2048.0f);
      }
    } else {
#pragma unroll
      for (int e = 0; e < 8; ++e) { v[e] = (float)a0[e]; v[8 + e] = (float)a1[e]; }
    }
  }

  bool cposa[4], pposa[4], cnega[4], pnega[4];
  int firstCpos = 0x7fffffff, firstCneg = 0x7fffffff;
#pragma unroll
  for (int j = 0; j < 4; ++j) {
    float g0 = v[j*4], g1 = v[j*4+1], g2 = v[j*4+2], g3 = v[j*4+3];
    cposa[j] = (g0 >  TAU) & (g1 >  TAU) & (g2 >  TAU) & (g3 >  TAU);
    pposa[j] = (g0 > -TAU) & (g1 > -TAU) & (g2 > -TAU) & (g3 > -TAU);
    cnega[j] = (g0 < -TAU) & (g1 < -TAU) & (g2 < -TAU) & (g3 < -TAU);
    pnega[j] = (g0 <  TAU) & (g1 <  TAU) & (g2 <  TAU) & (g3 <  TAU);
    int gi = (t << 2) + j;
    if (cposa[j] && gi < firstCpos) firstCpos = gi;
    if (cnega[j] && gi < firstCneg) firstCneg = gi;
  }
#pragma unroll
  for (int off = 32; off; off >>= 1) {
    firstCpos = min(firstCpos, __shfl_xor(firstCpos, off));
    firstCneg = min(firstCneg, __shfl_xor(firstCneg, off));
  }
  if ((t & 63) == 0) { sPos[t >> 6] = firstCpos; sNeg[t >> 6] = firstCneg; }
  __syncthreads();
  firstCpos = min(min(sPos[0], sPos[1]), min(sPos[2], sPos[3]));
  firstCneg = min(min(sNeg[0], sNeg[1]), min(sNeg[2], sNeg[3]));
  __syncthreads();

#pragma unroll
  for (int j = 0; j < 4; ++j) {
    int gi = (t << 2) + j;
    bool qual = (pposa[j] && !cposa[j] && gi <= firstCpos) ||
                (pnega[j] && !cnega[j] && gi <= firstCneg);
    if (qual) {
#pragma unroll
      for (int e = 0; e < 4; ++e) {
        if (fabsf(v[j*4+e]) < TAU) {
          int slot = atomicAdd(&nFix, 1);
          if (slot < 96) fixIdx[slot] = gi * 4 + e;
        }
      }
    }
  }
  __syncthreads();
  const int nf = min(nFix, 96);
  unsigned fixmask = 0;
  for (int i = 0; i < nf; ++i) {
    const int col = fixIdx[i];
    double s = 0.0;
    const float* wr = W + (size_t)col * K;
    if (Af) {
      const float* ar = Af + (size_t)row * K;
      for (int k = t; k < K; k += 256) s += (double)ar[k] * (double)wr[k];
    } else {
      const _Float16* ah = Ahi + (size_t)row * K;
      const _Float16* al = Alo + (size_t)row * K;
      for (int k = t; k < K; k += 256)
        s += ((double)(float)ah[k] + (double)(float)al[k] * (1.0 / 2048.0)) * (double)wr[k];
    }
#pragma unroll
    for (int off = 32; off; off >>= 1) s += __shfl_xor(s, off);
    if ((t & 63) == 0) sRed[t >> 6] = s;
    __syncthreads();
    if (t == 0)
      sVal = (float)(sRed[0] + sRed[1] + sRed[2] + sRed[3] + (double)bias[col]);
    __syncthreads();
    if ((col >> 4) == t) { v[col & 15] = sVal; fixmask |= 1u << (col & 15); }
    __syncthreads();
  }

  int fp = 0x7fffffff, fn = 0x7fffffff;
#pragma unroll
  for (int j = 0; j < 4; ++j) {
    bool ap = (v[j*4+0] > 0.f) & (v[j*4+1] > 0.f) & (v[j*4+2] > 0.f) & (v[j*4+3] > 0.f);
    bool an = (v[j*4+0] < 0.f) & (v[j*4+1] < 0.f) & (v[j*4+2] < 0.f) & (v[j*4+3] < 0.f);
    int g = (t << 2) + j;
    if (ap && g < fp) fp = g;
    if (an && g < fn) fn = g;
  }
#pragma unroll
  for (int off = 32; off; off >>= 1) {
    fp = min(fp, __shfl_xor(fp, off));
    fn = min(fn, __shfl_xor(fn, off));
  }
  if ((t & 63) == 0) { sPos[t >> 6] = fp; sNeg[t >> 6] = fn; }
  __syncthreads();
  fp = min(min(sPos[0], sPos[1]), min(sPos[2], sPos[3]));
  fn = min(min(sNeg[0], sNeg[1]), min(sNeg[2], sNeg[3]));
  const int act   = (fp == 0x7fffffff) ? -1 : fp;
  const int inact = (fn == 0x7fffffff) ? -1 : fn;

  unsigned chg = fixmask;
#pragma unroll
  for (int j = 0; j < 4; ++j) {
    int g = (t << 2) + j;
    if (g == act) {
      v[j*4+0] *= 2.f; v[j*4+1] *= 2.f; v[j*4+2] *= 2.f; v[j*4+3] *= 2.f;
      chg |= 0xFu << (j * 4);
    } else if (g == inact) {
      v[j*4+0] = v[j*4+1] = v[j*4+2] = v[j*4+3] = 0.f;
      chg |= 0xFu << (j * 4);
    }
  }
  while (chg) {
    int e = __ffs(chg) - 1; chg &= chg - 1;
    float val = v[e];
    _Float16 hh = (_Float16)val;
    zh[(t << 4) + e] = hh;
    if (zl) zl[(t << 4) + e] = (_Float16)((val - (float)hh) * 2048.0f);
  }
}

extern "C" void kernel_launch(void* const* d_in, const int* in_sizes, int n_in,
                              void* d_out, int out_size, void* d_ws, size_t ws_size,
                              hipStream_t stream) {
  const float* x  = (const float*)d_in[0];
  const float* W1 = (const float*)d_in[1];
  const float* b1 = (const float*)d_in[2];
  const float* W2 = (const float*)d_in[3];
  const float* b2 = (const float*)d_in[4];
  const float* W3 = (const float*)d_in[5];
  const float* b3 = (const float*)d_in[6];
  float* out = (float*)d_out;

  const int M = 8192, H = 4096, DIN = 1024, DOUT = 1024;

  // Scratch: 256 MiB, time-sliced aliasing (r11-proven layout).
  char* w = (char*)d_ws;
  _Float16* Z1hi = (_Float16*)(w + 0);
  _Float16* Z1lo = (_Float16*)(w + ((size_t)64 << 20));
  _Float16* Z2hi = (_Float16*)(w + ((size_t)128 << 20));
  _Float16* W2hi = (_Float16*)(w + ((size_t)192 << 20));
  // aliases (dead before their region's long-term owner is written)
  _Float16* xhi  = (_Float16*)(w + ((size_t)128 << 20));
  _Float16* xlo  = (_Float16*)(w + ((size_t)144 << 20));
  _Float16* W1hi = (_Float16*)(w + ((size_t)160 << 20));
  _Float16* W1lo = (_Float16*)(w + ((size_t)168 << 20));
  _Float16* W3hi = (_Float16*)(w + ((size_t)224 << 20));

  // One fused split pass: x (hi/lo), W1 (hi/lo), W2 (hi), W3 (hi).
  split4_kernel<<<2048, 256, 0, stream>>>(
      x,  xhi,  xlo,  (size_t)(M * DIN) >> 2,
      W1, W1hi, W1lo, (size_t)(H * DIN) >> 2,
      W2, W2hi,       (size_t)((size_t)H * H) >> 2,
      W3, W3hi,       (size_t)(DOUT * H) >> 2);

  // L1: Z1 = x @ W1^T + b1   (K=1024) — split-f16 precise, hi/lo out
  gemm_tri<0><<<dim3((H / BN) * (M / BM)), dim3(1024), 0, stream>>>(
      xhi, xlo, W1hi, W1lo, b1, Z1hi, Z1lo, (float*)nullptr, M, H, DIN, H / BN);
  sda_fix<<<M, 256, 0, stream>>>(Z1hi, Z1lo, x, (const _Float16*)nullptr,
                                 (const _Float16*)nullptr, W1, b1, H, DIN, 1e-4f);
  // L2: Z2 = Z1 @ W2^T + b2  (K=4096) — hi-only f16, 256x256, BK=64 epochs
  gemm_sq<<<dim3((H / 256) * (M / 256)), dim3(1024), 0, stream>>>(
      Z1hi, W2hi, b2, Z2hi, M, H, H, H / 256);
  sda_fix<<<M, 256, 0, stream>>>(Z2hi, (_Float16*)nullptr, (const float*)nullptr,
                                 Z1hi, Z1lo, W2, b2, H, H, 5e-3f);
  // L3: out = Z2 @ W3^T + b3 (N=1024) — hi-only
  gemm_tri<2><<<dim3((DOUT / BN) * (M / BM)), dim3(1024), 0, stream>>>(
      Z2hi, (const _Float16*)nullptr, W3hi, (const _Float16*)nullptr, b3,
      (_Float16*)nullptr, (_Float16*)nullptr, out, M, DOUT, H, DOUT / BN);
}